// Round 8
// baseline (309.795 us; speedup 1.0000x reference)
//
#include <hip/hip_runtime.h>
#include <hip/hip_bf16.h>
#include <stdint.h>

// ---------------------------------------------------------------------------
// DiagonalElman on MI355X (gfx950)
//   W_comb = W_x @ W_in                  (small bf16 GEMM, frag-order out)
//   [xproj | xw] = x @ [W_in ; W_comb]^T (fused bf16 GEMM, bf16 out)
//   scan: h_t = tanh(xw_t + a*h_{t-1} + b); cell = h * silu(xproj + b_gate)
//   out    = cell @ W_out^T              (bf16 GEMM, fp32 out)
//
// R11: B operand (weight panels, <=4MB, L2-resident) no longer staged in LDS
// — read directly global->register per tile (8 dwordx4/wave, issued first,
// latency hidden under A ds_reads + MFMA k0). R7 post-mortem: per-CU-tile
// LDS read stream (192 b128 ~ 2260cy) ~ MFMA stream (2483cy); with 2
// barrier-synced waves/SIMD in phase the pipes contend -> ~their sum.
// Cutting B from LDS: reads 192->128 b128, stage 64->32KB, LDS 128->64KB.
// Schedule (one barrier per K-tile, from R7):
//   { B gloads (b0,b1) | stage A(t+1) | A ds_reads k0 | MFMA k0 |
//     A ds_reads k1 | MFMA k1 | lgkmcnt(0) | vmcnt(0) | sched_barrier | BAR }
// Hazards: stage(t+1)->Abuf[(t+1)&1], last readers drained at t-1's
// lgkmcnt(0)+barrier; vmcnt(0)+barrier publishes staged A; B loads consumed
// in-tile by MFMA (compiler counted waits). Barrier counts wave-uniform.
// Fragment flat layout for [R x K] (16B units):
//   unit = (rb*KB + kb)*64 + lane,  rb=r>>4, kb=k>>5,
//   lane = (r&15) | (((k>>3)&3)<<4), elem j = k&7.
// ---------------------------------------------------------------------------

typedef __bf16 bf16x8 __attribute__((ext_vector_type(8)));
typedef float  f32x4  __attribute__((ext_vector_type(4)));

#define AS1 __attribute__((address_space(1)))
#define AS3 __attribute__((address_space(3)))

__device__ __forceinline__ unsigned short f2bf(float f) {
  uint32_t u = __float_as_uint(f);
  uint32_t r = (u + 0x7FFFu + ((u >> 16) & 1u)) >> 16;
  return (unsigned short)r;
}
__device__ __forceinline__ float bf2f(uint32_t h) {
  return __uint_as_float(h << 16);
}
__device__ __forceinline__ float tanh_fast(float x) {
  float e = __expf(2.0f * x);
  return 1.0f - 2.0f / (e + 1.0f);
}

// ---------------------------------------------------------------------------
// fp32 [R x K] row-major -> bf16 fragment order (bodies shared by kernels).
// ---------------------------------------------------------------------------
__device__ __forceinline__ void frag_rm_body(
    const float* __restrict__ W, unsigned short* __restrict__ out,
    int u, int K, int KB) {
  const int lane = u & 63;
  const int grp  = u >> 6;
  const int n = (grp / KB) * 16 + (lane & 15);
  const int k = (grp % KB) * 32 + ((lane >> 4) & 3) * 8;
  const float4* p = (const float4*)(W + (size_t)n * K + k);
  float4 a = p[0], b = p[1];
  union { unsigned short us[8]; uint4 v; } r;
  r.us[0] = f2bf(a.x); r.us[1] = f2bf(a.y); r.us[2] = f2bf(a.z); r.us[3] = f2bf(a.w);
  r.us[4] = f2bf(b.x); r.us[5] = f2bf(b.y); r.us[6] = f2bf(b.z); r.us[7] = f2bf(b.w);
  *(uint4*)(out + (size_t)u * 8) = r.v;
}

__device__ __forceinline__ void frag_tr_body(
    const float* __restrict__ W, unsigned short* __restrict__ out,
    int u, int N, int KB) {
  const int lane = u & 63;
  const int grp  = u >> 6;
  const int n = (grp / KB) * 16 + (lane & 15);
  const int k = (grp % KB) * 32 + ((lane >> 4) & 3) * 8;
  union { unsigned short us[8]; uint4 v; } r;
#pragma unroll
  for (int j = 0; j < 8; ++j) r.us[j] = f2bf(W[(size_t)(k + j) * N + n]);
  *(uint4*)(out + (size_t)u * 8) = r.v;
}

// one launch: blocks [0,xBlocks) swizzle x; then 4 weight jobs of wBlocks.
__global__ __launch_bounds__(256) void frag_all(
    const float* __restrict__ x,
    const float* __restrict__ Wx, const float* __restrict__ Win,
    const float* __restrict__ Wout,
    unsigned short* __restrict__ xfrag,
    unsigned short* __restrict__ WxF, unsigned short* __restrict__ WinTF,
    unsigned short* __restrict__ WcatF, unsigned short* __restrict__ WoutF,
    int Kd, int KB, int xBlocks, int wBlocks) {
  if (blockIdx.x < (unsigned)xBlocks) {
    const int u = blockIdx.x * 256 + threadIdx.x;
    frag_rm_body(x, xfrag, u, Kd, KB);
    return;
  }
  const int wb = blockIdx.x - xBlocks;
  const int job = wb / wBlocks;
  const int u = (wb - job * wBlocks) * 256 + threadIdx.x;
  if (job == 0)      frag_rm_body(Wx,  WxF,   u, Kd, KB);
  else if (job == 1) frag_tr_body(Win, WinTF, u, Kd, KB);
  else if (job == 2) frag_rm_body(Win, WcatF, u, Kd, KB);
  else               frag_rm_body(Wout, WoutF, u, Kd, KB);
}

// ---------------------------------------------------------------------------
// Small bf16 MFMA GEMM (128x128 tile, register-streaming, no LDS).
// SM: 0 = fp32 row-major C, 1 = bf16 row-major C, 2 = bf16 FRAGMENT-order C.
// ---------------------------------------------------------------------------
#define BM 128
#define BN 128

template <int SM>
__global__ __launch_bounds__(256) void gemm_frag(
    const unsigned short* __restrict__ Af, const unsigned short* __restrict__ Bf,
    void* __restrict__ Cv, int M, int N, int K) {
  const int tid  = threadIdx.x;
  const int lane = tid & 63;
  const int wave = tid >> 6;
  const int wrow = wave >> 1;
  const int wcol = wave & 1;
  const int rowBase = blockIdx.x * BM;
  const int colBase = blockIdx.y * BN;
  const int q   = lane >> 4;
  const int r16 = lane & 15;
  const int KB  = K >> 5;

  const unsigned short* ap[4];
  const unsigned short* bp[4];
#pragma unroll
  for (int i = 0; i < 4; ++i) {
    const int rb = (rowBase >> 4) + wrow * 4 + i;
    const int nb = (colBase >> 4) + wcol * 4 + i;
    ap[i] = Af + ((size_t)rb * KB * 64 + lane) * 8;
    bp[i] = Bf + ((size_t)nb * KB * 64 + lane) * 8;
  }

  f32x4 acc[4][4] = {};
  bf16x8 a0[4], b0[4];
#pragma unroll
  for (int i = 0; i < 4; ++i) {
    a0[i] = *(const bf16x8*)ap[i];
    b0[i] = *(const bf16x8*)bp[i];
  }

  for (int kb = 0; kb < KB; ++kb) {
    const size_t noff = (size_t)((kb + 1 < KB) ? kb + 1 : kb) * 512;
    bf16x8 a1[4], b1[4];
#pragma unroll
    for (int i = 0; i < 4; ++i) {
      a1[i] = *(const bf16x8*)(ap[i] + noff);
      b1[i] = *(const bf16x8*)(bp[i] + noff);
    }
#pragma unroll
    for (int i = 0; i < 4; ++i)
#pragma unroll
      for (int j = 0; j < 4; ++j)
        acc[i][j] = __builtin_amdgcn_mfma_f32_16x16x32_bf16(a0[i], b0[j], acc[i][j], 0, 0, 0);
#pragma unroll
    for (int i = 0; i < 4; ++i) { a0[i] = a1[i]; b0[i] = b1[i]; }
  }

  // epilogue: C/D layout col = lane&15, row = (lane>>4)*4 + reg
#pragma unroll
  for (int i = 0; i < 4; ++i) {
#pragma unroll
    for (int j = 0; j < 4; ++j) {
#pragma unroll
      for (int rg = 0; rg < 4; ++rg) {
        long long row = rowBase + wrow * 64 + i * 16 + q * 4 + rg;
        long long col = colBase + wcol * 64 + j * 16 + r16;
        float v = acc[i][j][rg];
        if (SM == 0) {
          ((float*)Cv)[row * (long long)N + col] = v;
        } else if (SM == 1) {
          ((unsigned short*)Cv)[row * (long long)N + col] = f2bf(v);
        } else {
          // fragment order: C treated as [M rows, N=K cols] operand
          const int KBo = N >> 5;
          long long unit = (((row >> 4) * (long long)KBo + (col >> 5)) << 6) +
                           ((row & 15) | ((((int)col >> 3) & 3) << 4));
          ((unsigned short*)Cv)[unit * 8 + (col & 7)] = f2bf(v);
        }
      }
    }
  }
}

// ---------------------------------------------------------------------------
// 256x256-tile bf16 MFMA GEMM; A via LDS (64KB dbuf), B direct from L2.
// C[m,n] = sum_k A[m,k]*B[n,k]. A,B fragment order. M,N%256==0, K%64==0,
// K/64>=2. 512 thr = 8 waves (2M x 4N), wave owns 128x64 output.
// blockIdx.x = M-tile, blockIdx.y = N-tile. ONE barrier per K-tile.
// ---------------------------------------------------------------------------
template <int SM>
__global__ __launch_bounds__(512, 2) void gemm256p(
    const unsigned short* __restrict__ Af, const unsigned short* __restrict__ Bf,
    void* __restrict__ Cv, int N, int K) {
  __shared__ __attribute__((aligned(128))) char smem[65536];
  const int tid  = threadIdx.x;
  const int lane = tid & 63;
  const int w    = tid >> 6;   // 0..7
  const int wr   = w >> 2;     // 0..1  (M half)
  const int wc   = w & 3;      // 0..3  (N quarter)
  const int KBg  = K >> 5;     // global 32-k block count
  const int NT   = K >> 6;     // 64-k tiles
  const int rbBase = blockIdx.x << 4;   // M-tile
  const int nbBase = blockIdx.y << 4;   // N-tile

  const char* Ab = (const char*)Af;
  const char* Bb = (const char*)Bf;

  // B fragment pointers: row-block nb = nbBase + wc*4 + j, k-half via offset.
  const char* Bp[4];
#pragma unroll
  for (int j = 0; j < 4; ++j) {
    const int nb = nbBase + (wc << 2) + j;
    Bp[j] = Bb + (((size_t)nb * KBg) << 10) + (size_t)(lane << 4);
  }

  f32x4 acc[8][4] = {};

#define STAGE_A(tt, hh)                                                         \
  {                                                                             \
    const int sb_ = (((tt) & 1) << 15) + ((hh) << 14);                          \
    _Pragma("unroll")                                                           \
    for (int i_ = 0; i_ < 2; ++i_) {                                            \
      const int g_ = (w << 1) + i_;                                             \
      const size_t go_ = (((size_t)(rbBase + g_) * KBg +                        \
                           (size_t)(((tt) << 1) + (hh))) << 10) +               \
                         (size_t)(lane << 4);                                   \
      __builtin_amdgcn_global_load_lds((AS1 void*)(Ab + go_),                   \
          (AS3 void*)(smem + sb_ + (g_ << 10)), 16, 0, 0);                      \
    }                                                                           \
  }
#define BAR() asm volatile("s_barrier" ::: "memory")

  // prologue: stage A tile0 (4 loads); drain; publish.
  STAGE_A(0, 0);
  STAGE_A(0, 1);
  asm volatile("s_waitcnt vmcnt(0)" ::: "memory");
  BAR();

  for (int t = 0; t < NT; ++t) {
    const char* LA = smem + ((t & 1) << 15);
    bf16x8 aL[4], aH[4], b0[4], b1[4];

    // B direct from global (L2-resident weight panel) — longest latency first
#pragma unroll
    for (int j = 0; j < 4; ++j) {
      b0[j] = *(const bf16x8*)(Bp[j]);
      b1[j] = *(const bf16x8*)(Bp[j] + 1024);
    }
    // stage A(t+1) into the other buffer (readers drained at t-1's barrier)
    if (t + 1 < NT) { STAGE_A(t + 1, 0); STAGE_A(t + 1, 1); }

    // A reads k0
#pragma unroll
    for (int i = 0; i < 4; ++i)
      aL[i] = *(const bf16x8*)(LA + (((wr << 3) + i) << 10) + (lane << 4));
#pragma unroll
    for (int i = 0; i < 4; ++i)
      aH[i] = *(const bf16x8*)(LA + (((wr << 3) + 4 + i) << 10) + (lane << 4));
    // MFMA k0 (A-k1 reads below are barrier-free -> compiler interleaves)
    __builtin_amdgcn_s_setprio(1);
#pragma unroll
    for (int i = 0; i < 4; ++i)
#pragma unroll
      for (int j = 0; j < 4; ++j)
        acc[i][j] = __builtin_amdgcn_mfma_f32_16x16x32_bf16(aL[i], b0[j], acc[i][j], 0, 0, 0);
#pragma unroll
    for (int i = 0; i < 4; ++i)
#pragma unroll
      for (int j = 0; j < 4; ++j)
        acc[4 + i][j] = __builtin_amdgcn_mfma_f32_16x16x32_bf16(aH[i], b0[j], acc[4 + i][j], 0, 0, 0);
    __builtin_amdgcn_s_setprio(0);

    // A reads k1
#pragma unroll
    for (int i = 0; i < 4; ++i)
      aL[i] = *(const bf16x8*)(LA + 16384 + (((wr << 3) + i) << 10) + (lane << 4));
#pragma unroll
    for (int i = 0; i < 4; ++i)
      aH[i] = *(const bf16x8*)(LA + 16384 + (((wr << 3) + 4 + i) << 10) + (lane << 4));
    __builtin_amdgcn_s_setprio(1);
#pragma unroll
    for (int i = 0; i < 4; ++i)
#pragma unroll
      for (int j = 0; j < 4; ++j)
        acc[i][j] = __builtin_amdgcn_mfma_f32_16x16x32_bf16(aL[i], b1[j], acc[i][j], 0, 0, 0);
#pragma unroll
    for (int i = 0; i < 4; ++i)
#pragma unroll
      for (int j = 0; j < 4; ++j)
        acc[4 + i][j] = __builtin_amdgcn_mfma_f32_16x16x32_bf16(aH[i], b1[j], acc[4 + i][j], 0, 0, 0);
    __builtin_amdgcn_s_setprio(0);

    // tile boundary: own ds_reads drained (staging can't race them), staged
    // A landed, nothing may sink past here (rule #18 fence).
    asm volatile("s_waitcnt lgkmcnt(0)" ::: "memory");
    if (t + 1 < NT) asm volatile("s_waitcnt vmcnt(0)" ::: "memory");
    __builtin_amdgcn_sched_barrier(0);
    BAR();

#pragma unroll
    for (int j = 0; j < 4; ++j) Bp[j] += 2048;   // next 64-k tile
  }
#undef STAGE_A
#undef BAR

  // epilogue: C/D layout col = lane&15, row = (lane>>4)*4 + reg
  const int q = lane >> 4, r16 = lane & 15;
#pragma unroll
  for (int i = 0; i < 8; ++i) {
#pragma unroll
    for (int j = 0; j < 4; ++j) {
#pragma unroll
      for (int rg = 0; rg < 4; ++rg) {
        long long row = (long long)blockIdx.x * 256 + wr * 128 + i * 16 + q * 4 + rg;
        long long col = (long long)blockIdx.y * 256 + wc * 64 + j * 16 + r16;
        float v = acc[i][j][rg];
        if (SM == 0) ((float*)Cv)[row * (long long)N + col] = v;
        else ((unsigned short*)Cv)[row * (long long)N + col] = f2bf(v);
      }
    }
  }
}

// ---------------------------------------------------------------------------
// Chunked diagonal scan, 8 channels/thread, 16B coalesced loads/stores.
// xcat: [B*T, 2D] row-major, cols 0..D-1 = xproj, D..2D-1 = xw.
// cell written in A-fragment order: 8 consecutive d = one 16B frag unit.
// ---------------------------------------------------------------------------
__global__ __launch_bounds__(256) void scan_kernel8(
    const unsigned short* __restrict__ xcat,
    const float* __restrict__ h0, const float* __restrict__ araw,
    const float* __restrict__ bvec, const float* __restrict__ bgate,
    unsigned short* __restrict__ cell, float* __restrict__ hfin,
    int Bv, int T, int D, int NC, int CH, int WARM) {
  const int idx = blockIdx.x * 256 + threadIdx.x;
  const int D8  = D >> 3;
  const int BD8 = Bv * D8;
  const int c = idx / BD8;
  if (c >= NC) return;
  const int ld = idx - c * BD8;
  const int b = ld / D8;
  const int d = (ld - b * D8) << 3;

  float av[8], bb[8], bg[8], h[8];
  *(float4*)&av[0] = *(const float4*)&araw[d];
  *(float4*)&av[4] = *(const float4*)&araw[d + 4];
  *(float4*)&bb[0] = *(const float4*)&bvec[d];
  *(float4*)&bb[4] = *(const float4*)&bvec[d + 4];
  *(float4*)&bg[0] = *(const float4*)&bgate[d];
  *(float4*)&bg[4] = *(const float4*)&bgate[d + 4];
#pragma unroll
  for (int j = 0; j < 8; ++j) av[j] = 1.0f / (1.0f + __expf(-av[j]));

  const int tb = c * CH;
  const int te = (tb + CH < T) ? (tb + CH) : T;
  int t0 = tb - WARM;
  if (t0 <= 0) {
    t0 = 0;
    *(float4*)&h[0] = *(const float4*)&h0[b * D + d];
    *(float4*)&h[4] = *(const float4*)&h0[b * D + d + 4];
  } else {
#pragma unroll
    for (int j = 0; j < 8; ++j) h[j] = 0.0f;
  }

  const int N2 = 2 * D;
  long long off = ((long long)b * T + t0) * N2 + D + d;   // xw
  for (int t = t0; t < tb; ++t) {                          // warm-up
    union { unsigned short u[8]; uint4 v; } wv;
    wv.v = *(const uint4*)&xcat[off];
#pragma unroll
    for (int j = 0; j < 8; ++j)
      h[j] = tanh_fast(__builtin_fmaf(av[j], h[j], bf2f(wv.u[j]) + bb[j]));
    off += N2;
  }
  long long offp = ((long long)b * T + tb) * N2 + d;       // xproj
  const int KBS = D * 16;                                  // shorts per 16-row blk
  const int dconst = ((d >> 5) << 9) + (((d >> 3) & 3) << 7);
  int m = b * T + tb;
  long long offc = (long long)(m >> 4) * KBS + ((m & 15) << 3) + dconst;
  for (int t = tb; t < te; ++t) {
    union { unsigned short u[8]; uint4 v; } wv, pv, ov;
    wv.v = *(const uint4*)&xcat[off];
    pv.v = *(const uint4*)&xcat[offp];
#pragma unroll
    for (int j = 0; j < 8; ++j) {
      h[j] = tanh_fast(__builtin_fmaf(av[j], h[j], bf2f(wv.u[j]) + bb[j]));
      float z = bf2f(pv.u[j]) + bg[j];
      float oo = h[j] * z / (1.0f + __expf(-z));
      ov.u[j] = f2bf(oo);
    }
    *(uint4*)&cell[offc] = ov.v;
    off += N2; offp += N2;
    ++m;
    offc += 8;
    if ((m & 15) == 0) offc += (long long)KBS - 128;
  }
  if (te == T) {
    *(float4*)&hfin[b * D + d]     = *(float4*)&h[0];
    *(float4*)&hfin[b * D + d + 4] = *(float4*)&h[4];
  }
}

// ---------------------------------------------------------------------------
extern "C" void kernel_launch(void* const* d_in, const int* in_sizes, int n_in,
                              void* d_out, int out_size, void* d_ws, size_t ws_size,
                              hipStream_t stream) {
  const float* x         = (const float*)d_in[0];
  const float* h0        = (const float*)d_in[1];
  const float* W_in      = (const float*)d_in[2];
  const float* W_x       = (const float*)d_in[3];
  const float* alpha_raw = (const float*)d_in[4];
  const float* b         = (const float*)d_in[5];
  const float* b_gate    = (const float*)d_in[6];
  const float* W_out     = (const float*)d_in[7];

  const int D  = in_sizes[4];
  const int BD = in_sizes[1];
  const int Bv = BD / D;
  const int M  = in_sizes[0] / D;   // B*T
  const int T  = M / Bv;
  const int KB = D >> 5;

  float* out  = (float*)d_out;                 // [M, D]
  float* hfin = out + (long long)M * D;        // [B, D]

  const size_t szXf  = (size_t)M * D * 2;      // bf16 frag [M,K=D]
  const size_t szCat = (size_t)M * D * 4;      // bf16 [M,2D] row-major
  const size_t szW   = (size_t)D * D * 2;      // bf16 [D,D]

  char* ws = (char*)d_ws;
  unsigned short* xfrag = (unsigned short*)ws; ws += szXf;
  unsigned short* xcat  = (unsigned short*)ws; ws += szCat;
  unsigned short* WcatF = (unsigned short*)ws; ws += 2 * szW;  // frag [2D, K=D]
  unsigned short* WoutF = (unsigned short*)ws; ws += szW;      // frag [D, K=D]
  // temporaries aliased inside xcat (dead before fused GEMM writes xcat):
  unsigned short* WxF    = xcat;
  unsigned short* WinTF  = xcat + (size_t)D * D;
  unsigned short* cell   = xfrag;              // xfrag dead after fused GEMM
  unsigned short* WcombF = WcatF + (size_t)D * D;

  const int xBlocks = (int)((size_t)M * D / 2048);
  const int wBlocks = (int)((size_t)D * D / 2048);

  frag_all<<<xBlocks + 4 * wBlocks, 256, 0, stream>>>(
      x, W_x, W_in, W_out, xfrag, WxF, WinTF, WcatF, WoutF,
      D, KB, xBlocks, wBlocks);

  // W_comb = W_x @ W_in, written DIRECTLY in fragment order into WcatF 2nd half
  gemm_frag<2><<<dim3(D / BM, D / BN), 256, 0, stream>>>(WxF, WinTF, WcombF, D, D, D);

  // [xproj | xw] = x @ Wcat^T : M x 2D (row-major bf16 out)
  gemm256p<1><<<dim3(M / 256, (2 * D) / 256), 512, 0, stream>>>(xfrag, WcatF, xcat, 2 * D, D);

  const int CH = 16;
  const int WARM = 8;
  const int NC = (T + CH - 1) / CH;
  const int total8 = NC * Bv * (D >> 3);
  scan_kernel8<<<(total8 + 255) / 256, 256, 0, stream>>>(
      xcat, h0, alpha_raw, b, b_gate, cell, hfin, Bv, T, D, NC, CH, WARM);

  // out = cell @ W_out^T (fp32 out)
  gemm256p<0><<<dim3(M / 256, D / 256), 512, 0, stream>>>(cell, WoutF, out, D, D);
}

// Round 9
// 291.020 us; speedup vs baseline: 1.0645x; 1.0645x over previous
//
#include <hip/hip_runtime.h>
#include <hip/hip_bf16.h>
#include <stdint.h>

// ---------------------------------------------------------------------------
// DiagonalElman on MI355X (gfx950)
//   W_comb = W_x @ W_in                  (small bf16 GEMM, frag-order out)
//   [xproj | xw] = x @ [W_in ; W_comb]^T (fused bf16 GEMM, bf16 out)
//   scan: h_t = tanh(xw_t + a*h_{t-1} + b); cell = h * silu(xproj + b_gate)
//   out    = cell @ W_out^T              (bf16 GEMM, fp32 out)
//
// R12 = R7 base (B back in LDS; R8's B-direct exposed L2 latency on the
// MFMA-dependent path, +900cy/tile) + WAVE-PHASE STAGGER:
//   wr=0 waves process k-halves in order k0->k1; wr=1 waves k1->k0.
//   Wave w runs on SIMD w&3, so each SIMD hosts one wave of each wr ->
//   at any instant one wave issues ds_reads while the other issues MFMAs
//   (dual-pipe overlap). k-half order within a tile is commutative in the
//   accumulator, so results are unchanged per output element.
// Schedule per tile (ONE barrier, from R7):
//   { reads kf | stage(t+1) | MFMA kf | reads ks | MFMA ks |
//     lgkmcnt(0) | vmcnt(0) | sched_barrier(0) | s_barrier }
// Hazards identical to R7: stage(t+1)->buf[(t+1)&1], last readers drained
// at t-1's lgkmcnt(0)+barrier; vmcnt(0)+barrier publishes staged tile.
// Fragment flat layout for [R x K] (16B units):
//   unit = (rb*KB + kb)*64 + lane,  rb=r>>4, kb=k>>5,
//   lane = (r&15) | (((k>>3)&3)<<4), elem j = k&7.
// ---------------------------------------------------------------------------

typedef __bf16 bf16x8 __attribute__((ext_vector_type(8)));
typedef float  f32x4  __attribute__((ext_vector_type(4)));

#define AS1 __attribute__((address_space(1)))
#define AS3 __attribute__((address_space(3)))

__device__ __forceinline__ unsigned short f2bf(float f) {
  uint32_t u = __float_as_uint(f);
  uint32_t r = (u + 0x7FFFu + ((u >> 16) & 1u)) >> 16;
  return (unsigned short)r;
}
__device__ __forceinline__ float bf2f(uint32_t h) {
  return __uint_as_float(h << 16);
}
__device__ __forceinline__ float tanh_fast(float x) {
  float e = __expf(2.0f * x);
  return 1.0f - 2.0f / (e + 1.0f);
}

// ---------------------------------------------------------------------------
// fp32 [R x K] row-major -> bf16 fragment order (bodies shared by kernels).
// ---------------------------------------------------------------------------
__device__ __forceinline__ void frag_rm_body(
    const float* __restrict__ W, unsigned short* __restrict__ out,
    int u, int K, int KB) {
  const int lane = u & 63;
  const int grp  = u >> 6;
  const int n = (grp / KB) * 16 + (lane & 15);
  const int k = (grp % KB) * 32 + ((lane >> 4) & 3) * 8;
  const float4* p = (const float4*)(W + (size_t)n * K + k);
  float4 a = p[0], b = p[1];
  union { unsigned short us[8]; uint4 v; } r;
  r.us[0] = f2bf(a.x); r.us[1] = f2bf(a.y); r.us[2] = f2bf(a.z); r.us[3] = f2bf(a.w);
  r.us[4] = f2bf(b.x); r.us[5] = f2bf(b.y); r.us[6] = f2bf(b.z); r.us[7] = f2bf(b.w);
  *(uint4*)(out + (size_t)u * 8) = r.v;
}

__device__ __forceinline__ void frag_tr_body(
    const float* __restrict__ W, unsigned short* __restrict__ out,
    int u, int N, int KB) {
  const int lane = u & 63;
  const int grp  = u >> 6;
  const int n = (grp / KB) * 16 + (lane & 15);
  const int k = (grp % KB) * 32 + ((lane >> 4) & 3) * 8;
  union { unsigned short us[8]; uint4 v; } r;
#pragma unroll
  for (int j = 0; j < 8; ++j) r.us[j] = f2bf(W[(size_t)(k + j) * N + n]);
  *(uint4*)(out + (size_t)u * 8) = r.v;
}

// one launch: blocks [0,xBlocks) swizzle x; then 4 weight jobs of wBlocks.
__global__ __launch_bounds__(256) void frag_all(
    const float* __restrict__ x,
    const float* __restrict__ Wx, const float* __restrict__ Win,
    const float* __restrict__ Wout,
    unsigned short* __restrict__ xfrag,
    unsigned short* __restrict__ WxF, unsigned short* __restrict__ WinTF,
    unsigned short* __restrict__ WcatF, unsigned short* __restrict__ WoutF,
    int Kd, int KB, int xBlocks, int wBlocks) {
  if (blockIdx.x < (unsigned)xBlocks) {
    const int u = blockIdx.x * 256 + threadIdx.x;
    frag_rm_body(x, xfrag, u, Kd, KB);
    return;
  }
  const int wb = blockIdx.x - xBlocks;
  const int job = wb / wBlocks;
  const int u = (wb - job * wBlocks) * 256 + threadIdx.x;
  if (job == 0)      frag_rm_body(Wx,  WxF,   u, Kd, KB);
  else if (job == 1) frag_tr_body(Win, WinTF, u, Kd, KB);
  else if (job == 2) frag_rm_body(Win, WcatF, u, Kd, KB);
  else               frag_rm_body(Wout, WoutF, u, Kd, KB);
}

// ---------------------------------------------------------------------------
// Small bf16 MFMA GEMM (128x128 tile, register-streaming, no LDS).
// SM: 0 = fp32 row-major C, 1 = bf16 row-major C, 2 = bf16 FRAGMENT-order C.
// ---------------------------------------------------------------------------
#define BM 128
#define BN 128

template <int SM>
__global__ __launch_bounds__(256) void gemm_frag(
    const unsigned short* __restrict__ Af, const unsigned short* __restrict__ Bf,
    void* __restrict__ Cv, int M, int N, int K) {
  const int tid  = threadIdx.x;
  const int lane = tid & 63;
  const int wave = tid >> 6;
  const int wrow = wave >> 1;
  const int wcol = wave & 1;
  const int rowBase = blockIdx.x * BM;
  const int colBase = blockIdx.y * BN;
  const int q   = lane >> 4;
  const int r16 = lane & 15;
  const int KB  = K >> 5;

  const unsigned short* ap[4];
  const unsigned short* bp[4];
#pragma unroll
  for (int i = 0; i < 4; ++i) {
    const int rb = (rowBase >> 4) + wrow * 4 + i;
    const int nb = (colBase >> 4) + wcol * 4 + i;
    ap[i] = Af + ((size_t)rb * KB * 64 + lane) * 8;
    bp[i] = Bf + ((size_t)nb * KB * 64 + lane) * 8;
  }

  f32x4 acc[4][4] = {};
  bf16x8 a0[4], b0[4];
#pragma unroll
  for (int i = 0; i < 4; ++i) {
    a0[i] = *(const bf16x8*)ap[i];
    b0[i] = *(const bf16x8*)bp[i];
  }

  for (int kb = 0; kb < KB; ++kb) {
    const size_t noff = (size_t)((kb + 1 < KB) ? kb + 1 : kb) * 512;
    bf16x8 a1[4], b1[4];
#pragma unroll
    for (int i = 0; i < 4; ++i) {
      a1[i] = *(const bf16x8*)(ap[i] + noff);
      b1[i] = *(const bf16x8*)(bp[i] + noff);
    }
#pragma unroll
    for (int i = 0; i < 4; ++i)
#pragma unroll
      for (int j = 0; j < 4; ++j)
        acc[i][j] = __builtin_amdgcn_mfma_f32_16x16x32_bf16(a0[i], b0[j], acc[i][j], 0, 0, 0);
#pragma unroll
    for (int i = 0; i < 4; ++i) { a0[i] = a1[i]; b0[i] = b1[i]; }
  }

  // epilogue: C/D layout col = lane&15, row = (lane>>4)*4 + reg
#pragma unroll
  for (int i = 0; i < 4; ++i) {
#pragma unroll
    for (int j = 0; j < 4; ++j) {
#pragma unroll
      for (int rg = 0; rg < 4; ++rg) {
        long long row = rowBase + wrow * 64 + i * 16 + q * 4 + rg;
        long long col = colBase + wcol * 64 + j * 16 + r16;
        float v = acc[i][j][rg];
        if (SM == 0) {
          ((float*)Cv)[row * (long long)N + col] = v;
        } else if (SM == 1) {
          ((unsigned short*)Cv)[row * (long long)N + col] = f2bf(v);
        } else {
          // fragment order: C treated as [M rows, N=K cols] operand
          const int KBo = N >> 5;
          long long unit = (((row >> 4) * (long long)KBo + (col >> 5)) << 6) +
                           ((row & 15) | ((((int)col >> 3) & 3) << 4));
          ((unsigned short*)Cv)[unit * 8 + (col & 7)] = f2bf(v);
        }
      }
    }
  }
}

// ---------------------------------------------------------------------------
// 256x256-tile bf16 MFMA GEMM, one barrier per K-tile, wave-phase stagger.
// C[m,n] = sum_k A[m,k]*B[n,k]. A,B fragment order. M,N%256==0, K%64==0,
// K/64>=2. 512 thr = 8 waves (2M x 4N), wave owns 128x64 output.
// blockIdx.x = M-tile, blockIdx.y = N-tile.
// LDS 128 KiB = 2 dbuf x (A 32KB + B 32KB), tile split into 2 K-halves;
// wr=0 waves consume k0 then k1, wr=1 waves k1 then k0 (SIMD w&3 hosts one
// wave of each wr -> ds_read and MFMA pipes overlap across the pair).
// ---------------------------------------------------------------------------
template <int SM>
__global__ __launch_bounds__(512, 2) void gemm256p(
    const unsigned short* __restrict__ Af, const unsigned short* __restrict__ Bf,
    void* __restrict__ Cv, int N, int K) {
  __shared__ __attribute__((aligned(128))) char smem[131072];
  const int tid  = threadIdx.x;
  const int lane = tid & 63;
  const int w    = tid >> 6;   // 0..7
  const int wr   = w >> 2;     // 0..1  (M half; also the k-half phase)
  const int wc   = w & 3;      // 0..3  (N quarter)
  const int KBg  = K >> 5;     // global 32-k block count
  const int NT   = K >> 6;     // 64-k tiles
  const int rbBase = blockIdx.x << 4;   // M-tile
  const int nbBase = blockIdx.y << 4;   // N-tile

  const char* Ab = (const char*)Af;
  const char* Bb = (const char*)Bf;

  // staggered k-half byte offsets within the 32KB operand region
  const int kf = wr ? 16384 : 0;     // first-consumed half
  const int ks = 16384 - kf;         // second-consumed half

  f32x4 acc[8][4] = {};

#define STAGE_A(tt, hh)                                                         \
  {                                                                             \
    const int sb_ = (((tt) & 1) << 16) + ((hh) << 14);                          \
    _Pragma("unroll")                                                           \
    for (int i_ = 0; i_ < 2; ++i_) {                                            \
      const int g_ = (w << 1) + i_;                                             \
      const size_t go_ = (((size_t)(rbBase + g_) * KBg +                        \
                           (size_t)(((tt) << 1) + (hh))) << 10) +               \
                         (size_t)(lane << 4);                                   \
      __builtin_amdgcn_global_load_lds((AS1 void*)(Ab + go_),                   \
          (AS3 void*)(smem + sb_ + (g_ << 10)), 16, 0, 0);                      \
    }                                                                           \
  }
#define STAGE_B(tt, hh)                                                         \
  {                                                                             \
    const int sb_ = (((tt) & 1) << 16) + 32768 + ((hh) << 14);                  \
    _Pragma("unroll")                                                           \
    for (int i_ = 0; i_ < 2; ++i_) {                                            \
      const int g_ = (w << 1) + i_;                                             \
      const size_t go_ = (((size_t)(nbBase + g_) * KBg +                        \
                           (size_t)(((tt) << 1) + (hh))) << 10) +               \
                         (size_t)(lane << 4);                                   \
      __builtin_amdgcn_global_load_lds((AS1 void*)(Bb + go_),                   \
          (AS3 void*)(smem + sb_ + (g_ << 10)), 16, 0, 0);                      \
    }                                                                           \
  }
#define BAR() asm volatile("s_barrier" ::: "memory")

  // prologue: stage tile0 (8 loads); drain; publish.
  STAGE_A(0, 0); STAGE_B(0, 0);
  STAGE_A(0, 1); STAGE_B(0, 1);
  asm volatile("s_waitcnt vmcnt(0)" ::: "memory");
  BAR();

  for (int t = 0; t < NT; ++t) {
    const char* LA = smem + ((t & 1) << 16);
    const char* LB = LA + 32768;
    bf16x8 aL[4], aH[4], b0[4], b1[4];

    // reads: first-consumed k-half (kf)
#pragma unroll
    for (int j = 0; j < 4; ++j)
      b0[j] = *(const bf16x8*)(LB + kf + (((wc << 2) + j) << 10) + (lane << 4));
#pragma unroll
    for (int i = 0; i < 4; ++i)
      aL[i] = *(const bf16x8*)(LA + kf + (((wr << 3) + i) << 10) + (lane << 4));
#pragma unroll
    for (int i = 0; i < 4; ++i)
      aH[i] = *(const bf16x8*)(LA + kf + (((wr << 3) + 4 + i) << 10) + (lane << 4));
    // stage tile t+1 into the other buffer (its readers drained at t-1's bar)
    if (t + 1 < NT) {
      STAGE_A(t + 1, 0); STAGE_B(t + 1, 0);
      STAGE_A(t + 1, 1); STAGE_B(t + 1, 1);
    }
    // MFMA on kf (other-wr wave on this SIMD is still in its ds_reads)
    __builtin_amdgcn_s_setprio(1);
#pragma unroll
    for (int i = 0; i < 4; ++i)
#pragma unroll
      for (int j = 0; j < 4; ++j)
        acc[i][j] = __builtin_amdgcn_mfma_f32_16x16x32_bf16(aL[i], b0[j], acc[i][j], 0, 0, 0);
#pragma unroll
    for (int i = 0; i < 4; ++i)
#pragma unroll
      for (int j = 0; j < 4; ++j)
        acc[4 + i][j] = __builtin_amdgcn_mfma_f32_16x16x32_bf16(aH[i], b0[j], acc[4 + i][j], 0, 0, 0);
    __builtin_amdgcn_s_setprio(0);

    // reads: second-consumed k-half (ks)
#pragma unroll
    for (int j = 0; j < 4; ++j)
      b1[j] = *(const bf16x8*)(LB + ks + (((wc << 2) + j) << 10) + (lane << 4));
#pragma unroll
    for (int i = 0; i < 4; ++i)
      aL[i] = *(const bf16x8*)(LA + ks + (((wr << 3) + i) << 10) + (lane << 4));
#pragma unroll
    for (int i = 0; i < 4; ++i)
      aH[i] = *(const bf16x8*)(LA + ks + (((wr << 3) + 4 + i) << 10) + (lane << 4));
    __builtin_amdgcn_s_setprio(1);
#pragma unroll
    for (int i = 0; i < 4; ++i)
#pragma unroll
      for (int j = 0; j < 4; ++j)
        acc[i][j] = __builtin_amdgcn_mfma_f32_16x16x32_bf16(aL[i], b1[j], acc[i][j], 0, 0, 0);
#pragma unroll
    for (int i = 0; i < 4; ++i)
#pragma unroll
      for (int j = 0; j < 4; ++j)
        acc[4 + i][j] = __builtin_amdgcn_mfma_f32_16x16x32_bf16(aH[i], b1[j], acc[4 + i][j], 0, 0, 0);
    __builtin_amdgcn_s_setprio(0);

    // tile boundary: own ds_reads drained (staging can't race them), staged
    // loads landed, nothing may sink past here (rule #18 fence).
    asm volatile("s_waitcnt lgkmcnt(0)" ::: "memory");
    if (t + 1 < NT) asm volatile("s_waitcnt vmcnt(0)" ::: "memory");
    __builtin_amdgcn_sched_barrier(0);
    BAR();
  }
#undef STAGE_A
#undef STAGE_B
#undef BAR

  // epilogue: C/D layout col = lane&15, row = (lane>>4)*4 + reg
  const int q = lane >> 4, r16 = lane & 15;
#pragma unroll
  for (int i = 0; i < 8; ++i) {
#pragma unroll
    for (int j = 0; j < 4; ++j) {
#pragma unroll
      for (int rg = 0; rg < 4; ++rg) {
        long long row = (long long)blockIdx.x * 256 + wr * 128 + i * 16 + q * 4 + rg;
        long long col = (long long)blockIdx.y * 256 + wc * 64 + j * 16 + r16;
        float v = acc[i][j][rg];
        if (SM == 0) ((float*)Cv)[row * (long long)N + col] = v;
        else ((unsigned short*)Cv)[row * (long long)N + col] = f2bf(v);
      }
    }
  }
}

// ---------------------------------------------------------------------------
// Chunked diagonal scan, 8 channels/thread, 16B coalesced loads/stores.
// xcat: [B*T, 2D] row-major, cols 0..D-1 = xproj, D..2D-1 = xw.
// cell written in A-fragment order: 8 consecutive d = one 16B frag unit.
// ---------------------------------------------------------------------------
__global__ __launch_bounds__(256) void scan_kernel8(
    const unsigned short* __restrict__ xcat,
    const float* __restrict__ h0, const float* __restrict__ araw,
    const float* __restrict__ bvec, const float* __restrict__ bgate,
    unsigned short* __restrict__ cell, float* __restrict__ hfin,
    int Bv, int T, int D, int NC, int CH, int WARM) {
  const int idx = blockIdx.x * 256 + threadIdx.x;
  const int D8  = D >> 3;
  const int BD8 = Bv * D8;
  const int c = idx / BD8;
  if (c >= NC) return;
  const int ld = idx - c * BD8;
  const int b = ld / D8;
  const int d = (ld - b * D8) << 3;

  float av[8], bb[8], bg[8], h[8];
  *(float4*)&av[0] = *(const float4*)&araw[d];
  *(float4*)&av[4] = *(const float4*)&araw[d + 4];
  *(float4*)&bb[0] = *(const float4*)&bvec[d];
  *(float4*)&bb[4] = *(const float4*)&bvec[d + 4];
  *(float4*)&bg[0] = *(const float4*)&bgate[d];
  *(float4*)&bg[4] = *(const float4*)&bgate[d + 4];
#pragma unroll
  for (int j = 0; j < 8; ++j) av[j] = 1.0f / (1.0f + __expf(-av[j]));

  const int tb = c * CH;
  const int te = (tb + CH < T) ? (tb + CH) : T;
  int t0 = tb - WARM;
  if (t0 <= 0) {
    t0 = 0;
    *(float4*)&h[0] = *(const float4*)&h0[b * D + d];
    *(float4*)&h[4] = *(const float4*)&h0[b * D + d + 4];
  } else {
#pragma unroll
    for (int j = 0; j < 8; ++j) h[j] = 0.0f;
  }

  const int N2 = 2 * D;
  long long off = ((long long)b * T + t0) * N2 + D + d;   // xw
  for (int t = t0; t < tb; ++t) {                          // warm-up
    union { unsigned short u[8]; uint4 v; } wv;
    wv.v = *(const uint4*)&xcat[off];
#pragma unroll
    for (int j = 0; j < 8; ++j)
      h[j] = tanh_fast(__builtin_fmaf(av[j], h[j], bf2f(wv.u[j]) + bb[j]));
    off += N2;
  }
  long long offp = ((long long)b * T + tb) * N2 + d;       // xproj
  const int KBS = D * 16;                                  // shorts per 16-row blk
  const int dconst = ((d >> 5) << 9) + (((d >> 3) & 3) << 7);
  int m = b * T + tb;
  long long offc = (long long)(m >> 4) * KBS + ((m & 15) << 3) + dconst;
  for (int t = tb; t < te; ++t) {
    union { unsigned short u[8]; uint4 v; } wv, pv, ov;
    wv.v = *(const uint4*)&xcat[off];
    pv.v = *(const uint4*)&xcat[offp];
#pragma unroll
    for (int j = 0; j < 8; ++j) {
      h[j] = tanh_fast(__builtin_fmaf(av[j], h[j], bf2f(wv.u[j]) + bb[j]));
      float z = bf2f(pv.u[j]) + bg[j];
      float oo = h[j] * z / (1.0f + __expf(-z));
      ov.u[j] = f2bf(oo);
    }
    *(uint4*)&cell[offc] = ov.v;
    off += N2; offp += N2;
    ++m;
    offc += 8;
    if ((m & 15) == 0) offc += (long long)KBS - 128;
  }
  if (te == T) {
    *(float4*)&hfin[b * D + d]     = *(float4*)&h[0];
    *(float4*)&hfin[b * D + d + 4] = *(float4*)&h[4];
  }
}

// ---------------------------------------------------------------------------
extern "C" void kernel_launch(void* const* d_in, const int* in_sizes, int n_in,
                              void* d_out, int out_size, void* d_ws, size_t ws_size,
                              hipStream_t stream) {
  const float* x         = (const float*)d_in[0];
  const float* h0        = (const float*)d_in[1];
  const float* W_in      = (const float*)d_in[2];
  const float* W_x       = (const float*)d_in[3];
  const float* alpha_raw = (const float*)d_in[4];
  const float* b         = (const float*)d_in[5];
  const float* b_gate    = (const float*)d_in[6];
  const float* W_out     = (const float*)d_in[7];

  const int D  = in_sizes[4];
  const int BD = in_sizes[1];
  const int Bv = BD / D;
  const int M  = in_sizes[0] / D;   // B*T
  const int T  = M / Bv;
  const int KB = D >> 5;

  float* out  = (float*)d_out;                 // [M, D]
  float* hfin = out + (long long)M * D;        // [B, D]

  const size_t szXf  = (size_t)M * D * 2;      // bf16 frag [M,K=D]
  const size_t szCat = (size_t)M * D * 4;      // bf16 [M,2D] row-major
  const size_t szW   = (size_t)D * D * 2;      // bf16 [D,D]

  char* ws = (char*)d_ws;
  unsigned short* xfrag = (unsigned short*)ws; ws += szXf;
  unsigned short* xcat  = (unsigned short*)ws; ws += szCat;
  unsigned short* WcatF = (unsigned short*)ws; ws += 2 * szW;  // frag [2D, K=D]
  unsigned short* WoutF = (unsigned short*)ws; ws += szW;      // frag [D, K=D]
  // temporaries aliased inside xcat (dead before fused GEMM writes xcat):
  unsigned short* WxF    = xcat;
  unsigned short* WinTF  = xcat + (size_t)D * D;
  unsigned short* cell   = xfrag;              // xfrag dead after fused GEMM
  unsigned short* WcombF = WcatF + (size_t)D * D;

  const int xBlocks = (int)((size_t)M * D / 2048);
  const int wBlocks = (int)((size_t)D * D / 2048);

  frag_all<<<xBlocks + 4 * wBlocks, 256, 0, stream>>>(
      x, W_x, W_in, W_out, xfrag, WxF, WinTF, WcatF, WoutF,
      D, KB, xBlocks, wBlocks);

  // W_comb = W_x @ W_in, written DIRECTLY in fragment order into WcatF 2nd half
  gemm_frag<2><<<dim3(D / BM, D / BN), 256, 0, stream>>>(WxF, WinTF, WcombF, D, D, D);

  // [xproj | xw] = x @ Wcat^T : M x 2D (row-major bf16 out)
  gemm256p<1><<<dim3(M / 256, (2 * D) / 256), 512, 0, stream>>>(xfrag, WcatF, xcat, 2 * D, D);

  const int CH = 16;
  const int WARM = 8;
  const int NC = (T + CH - 1) / CH;
  const int total8 = NC * Bv * (D >> 3);
  scan_kernel8<<<(total8 + 255) / 256, 256, 0, stream>>>(
      xcat, h0, alpha_raw, b, b_gate, cell, hfin, Bv, T, D, NC, CH, WARM);

  // out = cell @ W_out^T (fp32 out)
  gemm256p<0><<<dim3(M / 256, D / 256), 512, 0, stream>>>(cell, WoutF, out, D, D);
}